// Round 1
// baseline (2011.376 us; speedup 1.0000x reference)
//
#include <hip/hip_runtime.h>

#define NEDGES 1600000
#define NNODES 100000
#define NF 128

// ---------------------------------------------------------------------------
// Kernel 1: scatter-add edge features into per-node sum rows (d_out) + counts.
// One wave (64 lanes) per edge: lane i handles features [2i, 2i+1] via float2.
// Edge row = 512B contiguous -> one fully-coalesced wave load.
// ---------------------------------------------------------------------------
__global__ __launch_bounds__(256) void gcn_scatter(
        const float* __restrict__ edge, const int* __restrict__ dst,
        float* __restrict__ sums, float* __restrict__ counts) {
    const int lane = threadIdx.x & 63;
    const int wid  = (int)((blockIdx.x * (unsigned)blockDim.x + threadIdx.x) >> 6);
    const int nw   = (int)((gridDim.x * (unsigned)blockDim.x) >> 6);
    for (int e = wid; e < NEDGES; e += nw) {
        const int d = dst[e];  // wave-uniform
        const float2 v =
            *reinterpret_cast<const float2*>(edge + (size_t)e * NF + lane * 2);
        float* s = sums + (size_t)d * NF + lane * 2;
        atomicAdd(s, v.x);
        atomicAdd(s + 1, v.y);
        if (lane == 0) atomicAdd(counts + d, 1.0f);
    }
}

// ---------------------------------------------------------------------------
// Kernel 2: in-place per-node transform on d_out:
//   row <- relu(W @ (row / max(count,1)) + b)
// W staged in LDS, padded stride 132 (128 would be a 32-way bank conflict:
// lanes read W[j][k] with j=lane -> all the same bank at stride 128).
// 8 nodes per block-iteration; each thread computes feature j for 4 nodes,
// so each W element read from LDS feeds 4 FMAs.
// ---------------------------------------------------------------------------
__global__ __launch_bounds__(256) void gcn_transform(
        const float* __restrict__ counts, const float* __restrict__ W,
        const float* __restrict__ b, float* __restrict__ io) {
    __shared__ float Ws[NF][NF + 4];
    __shared__ float aggs[8][NF];
    const int tid = threadIdx.x;

    for (int i = tid; i < NF * NF; i += 256) {
        Ws[i >> 7][i & 127] = W[i];
    }
    const int j   = tid & 127;  // output feature
    const int sub = tid >> 7;   // node subgroup: handles nodes sub*4 .. sub*4+3
    const float bj = b[j];
    __syncthreads();

    for (int base = blockIdx.x * 8; base < NNODES; base += gridDim.x * 8) {
        // Cooperative load of 8 mean rows into LDS.
        for (int i = tid; i < 8 * NF; i += 256) {
            const int n = base + (i >> 7);
            float v = 0.0f;
            if (n < NNODES) {
                const float c = counts[n];
                v = io[(size_t)n * NF + (i & 127)] * (1.0f / fmaxf(c, 1.0f));
            }
            aggs[i >> 7][i & 127] = v;
        }
        __syncthreads();

        float acc0 = bj, acc1 = bj, acc2 = bj, acc3 = bj;
        const int n0 = base + sub * 4;
        #pragma unroll
        for (int k = 0; k < NF; k += 4) {
            const float4 w  = *reinterpret_cast<const float4*>(&Ws[j][k]);
            const float4 a0 = *reinterpret_cast<const float4*>(&aggs[sub * 4 + 0][k]);
            const float4 a1 = *reinterpret_cast<const float4*>(&aggs[sub * 4 + 1][k]);
            const float4 a2 = *reinterpret_cast<const float4*>(&aggs[sub * 4 + 2][k]);
            const float4 a3 = *reinterpret_cast<const float4*>(&aggs[sub * 4 + 3][k]);
            acc0 = fmaf(a0.x, w.x, acc0); acc0 = fmaf(a0.y, w.y, acc0);
            acc0 = fmaf(a0.z, w.z, acc0); acc0 = fmaf(a0.w, w.w, acc0);
            acc1 = fmaf(a1.x, w.x, acc1); acc1 = fmaf(a1.y, w.y, acc1);
            acc1 = fmaf(a1.z, w.z, acc1); acc1 = fmaf(a1.w, w.w, acc1);
            acc2 = fmaf(a2.x, w.x, acc2); acc2 = fmaf(a2.y, w.y, acc2);
            acc2 = fmaf(a2.z, w.z, acc2); acc2 = fmaf(a2.w, w.w, acc2);
            acc3 = fmaf(a3.x, w.x, acc3); acc3 = fmaf(a3.y, w.y, acc3);
            acc3 = fmaf(a3.z, w.z, acc3); acc3 = fmaf(a3.w, w.w, acc3);
        }

        if (n0 + 0 < NNODES) io[(size_t)(n0 + 0) * NF + j] = fmaxf(acc0, 0.0f);
        if (n0 + 1 < NNODES) io[(size_t)(n0 + 1) * NF + j] = fmaxf(acc1, 0.0f);
        if (n0 + 2 < NNODES) io[(size_t)(n0 + 2) * NF + j] = fmaxf(acc2, 0.0f);
        if (n0 + 3 < NNODES) io[(size_t)(n0 + 3) * NF + j] = fmaxf(acc3, 0.0f);
        __syncthreads();  // protect aggs before next iteration's overwrite
    }
}

extern "C" void kernel_launch(void* const* d_in, const int* in_sizes, int n_in,
                              void* d_out, int out_size, void* d_ws, size_t ws_size,
                              hipStream_t stream) {
    const float* edge = (const float*)d_in[0];
    const int*   dst  = (const int*)d_in[1];
    const float* W    = (const float*)d_in[2];
    const float* b    = (const float*)d_in[3];
    float* out    = (float*)d_out;            // doubles as the sum accumulator
    float* counts = (float*)d_ws;             // NNODES floats = 400 KB

    // Zero accumulators every call (harness poisons once; graph replays reuse).
    hipMemsetAsync(out, 0, (size_t)NNODES * NF * sizeof(float), stream);
    hipMemsetAsync(counts, 0, (size_t)NNODES * sizeof(float), stream);

    // Scatter: 2048 blocks * 4 waves = 8192 waves (full resident capacity),
    // ~196 edges per wave.
    gcn_scatter<<<2048, 256, 0, stream>>>(edge, dst, out, counts);

    // Transform: LDS = 71.7 KB -> 2 blocks/CU; 1024 blocks, ~12 tiles each.
    gcn_transform<<<1024, 256, 0, stream>>>(counts, W, b, out);
}

// Round 2
// 643.985 us; speedup vs baseline: 3.1233x; 3.1233x over previous
//
#include <hip/hip_runtime.h>

#define NEDGES 1600000
#define NNODES 100000
#define NF 128

typedef short s16x8 __attribute__((ext_vector_type(8)));
typedef float f32x4 __attribute__((ext_vector_type(4)));

// ---- workspace byte layout ----
#define CNT_B    0u         // int[100000]      400000 B
#define ROWPTR_B 400000u    // int[100001]      400004 B
#define CURSOR_B 800016u    // int[100000]      400000 B
#define EIDS_B   1200016u   // int[1600000]    6400000 B
#define WBF_B    7600016u   // ushort[16384]     32768 B
// total ~7.63 MB

static __device__ __forceinline__ unsigned short f2bf(float x) {
    unsigned u = __float_as_uint(x);
    unsigned r = (u + 0x7fffu + ((u >> 16) & 1u)) >> 16;  // RNE
    return (unsigned short)r;
}

__global__ __launch_bounds__(256) void k_hist(const int* __restrict__ dst,
                                              int* __restrict__ cnt) {
    int i = blockIdx.x * 256 + threadIdx.x;
    if (i < NEDGES) atomicAdd(&cnt[dst[i]], 1);
}

// Single-block exclusive scan over cnt -> rowptr (+ sentinel) and cursor copy.
__global__ __launch_bounds__(1024) void k_scan(const int* __restrict__ cnt,
                                               int* __restrict__ rowptr,
                                               int* __restrict__ cursor) {
    const int t = threadIdx.x;
    const int lo = t * 98;
    const int hi = min(lo + 98, NNODES);
    int s = 0;
    for (int i = lo; i < hi; ++i) s += cnt[i];
    __shared__ int ps[1024];
    ps[t] = s;
    __syncthreads();
    for (int off = 1; off < 1024; off <<= 1) {
        int v = (t >= off) ? ps[t - off] : 0;
        __syncthreads();
        ps[t] += v;
        __syncthreads();
    }
    int base = (t == 0) ? 0 : ps[t - 1];  // exclusive prefix
    for (int i = lo; i < hi; ++i) {
        rowptr[i] = base;
        cursor[i] = base;
        base += cnt[i];
    }
    if (t == 1023) rowptr[NNODES] = NEDGES;
}

__global__ __launch_bounds__(256) void k_fill(const int* __restrict__ dst,
                                              int* __restrict__ cursor,
                                              int* __restrict__ eids) {
    int i = blockIdx.x * 256 + threadIdx.x;
    if (i < NEDGES) {
        int p = atomicAdd(&cursor[dst[i]], 1);
        eids[p] = i;
    }
}

__global__ __launch_bounds__(256) void k_wconv(const float* __restrict__ W,
                                               unsigned short* __restrict__ Wb) {
    int i = blockIdx.x * 256 + threadIdx.x;
    if (i < NF * NF) Wb[i] = f2bf(W[i]);
}

// ---------------------------------------------------------------------------
// Fused gather + mean + (W @ agg + b) + ReLU.
// Block = 256 threads = 4 waves, handles 16 nodes.
// Gather: wave w gathers nodes {w, w+4, w+8, w+12}; lane handles feats 2l,2l+1
//   (float2 -> 512 B coalesced per edge row). Mean -> bf16 pair -> swizzled LDS.
// LDS agg tile: 16 rows x 256 B, byte ^= (row&7)<<4 (stride-256 rows would be a
//   16-way bank conflict on the MFMA b128 reads otherwise).
// MFMA: wave w computes j-tiles {2w, 2w+1}: 16 nodes x 16 feats, K=128 via
//   4 x mfma_f32_16x16x32_bf16. W fragments preloaded to registers (L1-hot).
// D layout (verified m89): col = lane&15, row = (lane>>4)*4 + reg.
// ---------------------------------------------------------------------------
__global__ __launch_bounds__(256) void k_fused(
        const float* __restrict__ edge, const int* __restrict__ rowptr,
        const int* __restrict__ eids, const unsigned short* __restrict__ Wb,
        const float* __restrict__ bias, float* __restrict__ out) {
    __shared__ __align__(16) char aggb[16 * 256];
    const int tid  = threadIdx.x;
    const int lane = tid & 63;
    const int wv   = tid >> 6;      // wave 0..3
    const int l15  = lane & 15;
    const int l4   = lane >> 4;
    const int n0   = blockIdx.x * 16;

    // Preload W fragments: B[k][n] = W[j0+n][k]; lane -> n=l15, k=(l4*8..+8).
    s16x8 wf[2][4];
    #pragma unroll
    for (int t = 0; t < 2; ++t) {
        const int j0 = (wv * 2 + t) * 16;
        #pragma unroll
        for (int ks = 0; ks < 4; ++ks) {
            wf[t][ks] = *(const s16x8*)((const char*)Wb +
                                        (j0 + l15) * 256 + ks * 64 + l4 * 16);
        }
    }

    // Gather phase.
    #pragma unroll
    for (int nn = 0; nn < 4; ++nn) {
        const int lr = wv + nn * 4;          // local row = node - n0
        const int n  = n0 + lr;
        const int s  = rowptr[n];
        const int e1 = rowptr[n + 1];
        float a0 = 0.f, a1 = 0.f;
        int e = s;
        for (; e + 4 <= e1; e += 4) {
            const int i0 = eids[e], i1 = eids[e + 1];
            const int i2 = eids[e + 2], i3 = eids[e + 3];
            const float2 v0 = *(const float2*)(edge + (size_t)i0 * NF + lane * 2);
            const float2 v1 = *(const float2*)(edge + (size_t)i1 * NF + lane * 2);
            const float2 v2 = *(const float2*)(edge + (size_t)i2 * NF + lane * 2);
            const float2 v3 = *(const float2*)(edge + (size_t)i3 * NF + lane * 2);
            a0 += (v0.x + v1.x) + (v2.x + v3.x);
            a1 += (v0.y + v1.y) + (v2.y + v3.y);
        }
        for (; e < e1; ++e) {
            const float2 v = *(const float2*)(edge + (size_t)eids[e] * NF + lane * 2);
            a0 += v.x; a1 += v.y;
        }
        const float inv = 1.f / fmaxf((float)(e1 - s), 1.f);
        a0 *= inv; a1 *= inv;
        const unsigned pk = (unsigned)f2bf(a0) | ((unsigned)f2bf(a1) << 16);
        const int byt = ((lr * 256 + lane * 4) ^ ((lr & 7) << 4));
        *(unsigned*)(aggb + byt) = pk;
    }
    __syncthreads();

    // MFMA phase: A[m][k] = agg[n0+m][k] from swizzled LDS.
    #pragma unroll
    for (int t = 0; t < 2; ++t) {
        const int j0 = (wv * 2 + t) * 16;
        f32x4 acc = {0.f, 0.f, 0.f, 0.f};
        #pragma unroll
        for (int ks = 0; ks < 4; ++ks) {
            const int byt = ((l15 * 256 + ks * 64 + l4 * 16) ^ ((l15 & 7) << 4));
            const s16x8 av = *(const s16x8*)(aggb + byt);
            acc = __builtin_amdgcn_mfma_f32_16x16x32_bf16(av, wf[t][ks], acc, 0, 0, 0);
        }
        const float bj = bias[j0 + l15];
        #pragma unroll
        for (int r = 0; r < 4; ++r) {
            const int m = l4 * 4 + r;
            out[(size_t)(n0 + m) * NF + j0 + l15] = fmaxf(acc[r] + bj, 0.f);
        }
    }
}

extern "C" void kernel_launch(void* const* d_in, const int* in_sizes, int n_in,
                              void* d_out, int out_size, void* d_ws, size_t ws_size,
                              hipStream_t stream) {
    const float* edge = (const float*)d_in[0];
    const int*   dst  = (const int*)d_in[1];
    const float* W    = (const float*)d_in[2];
    const float* b    = (const float*)d_in[3];
    float* out = (float*)d_out;

    char* ws = (char*)d_ws;
    int*            cnt    = (int*)(ws + CNT_B);
    int*            rowptr = (int*)(ws + ROWPTR_B);
    int*            cursor = (int*)(ws + CURSOR_B);
    int*            eids   = (int*)(ws + EIDS_B);
    unsigned short* Wb     = (unsigned short*)(ws + WBF_B);

    hipMemsetAsync(cnt, 0, (size_t)NNODES * sizeof(int), stream);

    k_wconv<<<(NF * NF + 255) / 256, 256, 0, stream>>>(W, Wb);
    k_hist<<<(NEDGES + 255) / 256, 256, 0, stream>>>(dst, cnt);
    k_scan<<<1, 1024, 0, stream>>>(cnt, rowptr, cursor);
    k_fill<<<(NEDGES + 255) / 256, 256, 0, stream>>>(dst, cursor, eids);
    k_fused<<<NNODES / 16, 256, 0, stream>>>(edge, rowptr, eids, Wb, b, out);
}